// Round 3
// baseline (229.898 us; speedup 1.0000x reference)
//
#include <hip/hip_runtime.h>

#pragma clang fp contract(off)

#define B_    512
#define N_    16384
#define A_    64
#define TPB   1024
#define ITERS 4              // N_ / (TPB*4) elements per thread = 16
#define CAP   2048

// One block per batch. Centroid (bit-exact numpy order) -> distances ->
// exact top-k threshold via adaptive-monotone-bucket radix select ->
// both mask writes. No dist16 array: selection is a (bits,index) threshold.
__global__ __launch_bounds__(TPB, 8) void fused_kernel(
    const float* __restrict__ pos,   const float* __restrict__ mask,
    const float* __restrict__ apos,  const float* __restrict__ amask,
    const int*   __restrict__ topk_ptr,
    float* __restrict__ out0, float* __restrict__ out1)
{
#pragma clang fp contract(off)
    __shared__ unsigned       hist[2048];      // 8 KB adaptive buckets
    __shared__ unsigned       cand_bits[CAP];  // 8 KB boundary candidates
    __shared__ unsigned short cand_idx[CAP];   // 4 KB
    __shared__ float          s_c[3];
    __shared__ unsigned       wmin[16], wmax[16];
    __shared__ unsigned       s_minb, s_shift, s_g, s_cum, s_ncand, s_k;
    __shared__ unsigned       s_Tb, s_Ti;      // selection threshold pair

    const int tid  = threadIdx.x;
    const int lane = tid & 63;
    const int wid  = tid >> 6;
    const int b    = blockIdx.x;
    const float* __restrict__ p = pos  + (size_t)b * N_ * 3;
    const float* __restrict__ m = mask + (size_t)b * N_;

    hist[tid]        = 0u;
    hist[tid + 1024] = 0u;
    if (tid == 0) { s_ncand = 0u; s_Tb = 0u; s_Ti = 0u; }

    // ---- wave 0: centroid straight from global, bit-exact numpy orders ----
    if (tid < 64) {
        const float* ap = apos  + (size_t)b * (A_ * 3);
        const float* am = amask + (size_t)b * A_;
        float comp = 0.0f, ms = 0.0f;
        if (tid < 3) {                       // axis=-2 sequential accumulate
            comp = ap[tid];
            for (int a = 1; a < A_; ++a) comp += ap[a * 3 + tid];
        }
        if (tid == 3) {                      // numpy pairwise-8 for n=64
            float r0 = am[0], r1 = am[1], r2 = am[2], r3 = am[3];
            float r4 = am[4], r5 = am[5], r6 = am[6], r7 = am[7];
            for (int i = 8; i < A_; i += 8) {
                r0 += am[i + 0]; r1 += am[i + 1]; r2 += am[i + 2]; r3 += am[i + 3];
                r4 += am[i + 4]; r5 += am[i + 5]; r6 += am[i + 6]; r7 += am[i + 7];
            }
            ms = ((r0 + r1) + (r2 + r3)) + ((r4 + r5) + (r6 + r7));
        }
        ms = __shfl(ms, 3, 64);
        if (tid < 3) s_c[tid] = comp / ms;   // correctly-rounded fp32 divide
        if (tid == 4) {
            int kk = *topk_ptr;
            if (kk < 0)  kk = 0;
            if (kk > N_) kk = N_;
            s_k = (unsigned)kk;
        }
    }
    __syncthreads();                                         // B1

    const float cx = s_c[0], cy = s_c[1], cz = s_c[2];
    const unsigned k = s_k;

    // ---- Phase A: distances (bit-exact), bits+mask in registers ----------
    unsigned rbits[ITERS * 4];
    float    rm16[ITERS * 4];
    unsigned mn = 0xFFFFFFFFu, mx = 0u;
#pragma unroll
    for (int it2 = 0; it2 < ITERS; ++it2) {
        const int i0 = it2 * (TPB * 4) + tid * 4;
        const float4 pa = *(const float4*)(p + (size_t)i0 * 3);
        const float4 pb = *(const float4*)(p + (size_t)i0 * 3 + 4);
        const float4 pc = *(const float4*)(p + (size_t)i0 * 3 + 8);
        const float4 mv = *(const float4*)(m + i0);
        const float px[4] = {pa.x, pa.w, pb.z, pc.y};
        const float py[4] = {pa.y, pb.x, pb.w, pc.z};
        const float pz[4] = {pa.z, pb.y, pc.x, pc.w};
        const float mm[4] = {mv.x, mv.y, mv.z, mv.w};
#pragma unroll
        for (int j = 0; j < 4; ++j) {
            float dx = cx - px[j], dy = cy - py[j], dz = cz - pz[j];
            float dx2 = dx * dx, dy2 = dy * dy, dz2 = dz * dz;
            float s = (dx2 + dy2) + dz2;     // numpy last-axis sum order
            s = s + 1e-12f;
            float d = sqrtf(s);              // correctly rounded
            float im = (1.0f - mm[j]) * 1e10f;
            d = d + im;
            const unsigned bits = __float_as_uint(d);  // monotone, d > 0
            rbits[it2 * 4 + j] = bits;
            rm16[it2 * 4 + j]  = mm[j];
            mn = min(mn, bits); mx = max(mx, bits);
        }
    }
    // wave min/max butterfly, then block combine
#pragma unroll
    for (int off = 32; off >= 1; off >>= 1) {
        mn = min(mn, (unsigned)__shfl_xor((int)mn, off, 64));
        mx = max(mx, (unsigned)__shfl_xor((int)mx, off, 64));
    }
    if (lane == 0) { wmin[wid] = mn; wmax[wid] = mx; }
    __syncthreads();                                         // B2
    if (tid < 64) {
        unsigned a  = (tid < 16) ? wmin[tid] : 0xFFFFFFFFu;
        unsigned bx = (tid < 16) ? wmax[tid] : 0u;
#pragma unroll
        for (int off = 8; off >= 1; off >>= 1) {
            a  = min(a,  (unsigned)__shfl_xor((int)a,  off, 64));
            bx = max(bx, (unsigned)__shfl_xor((int)bx, off, 64));
        }
        if (tid == 0) {
            s_minb = a;
            const unsigned range = bx - a;
            s_shift = (range == 0u) ? 0u : (unsigned)(32 - __clz(range));
        }
    }
    __syncthreads();                                         // B3

    // ---- Phase B: adaptive histogram (monotone bucket, ~8/bucket) --------
    const unsigned minb = s_minb, sh = s_shift;
#pragma unroll
    for (int x = 0; x < ITERS * 4; ++x) {
        const unsigned idx =
            (unsigned)(((unsigned long long)(rbits[x] - minb) << 11) >> sh);
        atomicAdd(&hist[idx], 1u);
    }

    if (k > 0) {
        __syncthreads();                                     // B4
        // ---- Phase C: wave-0 two-level scan finds boundary bucket g ------
        if (tid < 64) {
            unsigned ssum = 0;
            const uint4* hp = (const uint4*)&hist[tid * 32];
#pragma unroll
            for (int r = 0; r < 8; ++r) {
                const uint4 h4 = hp[r];
                ssum += h4.x + h4.y + h4.z + h4.w;
            }
            unsigned incl = ssum;
#pragma unroll
            for (int off = 1; off < 64; off <<= 1) {
                const unsigned v = (unsigned)__shfl_up((int)incl, off, 64);
                if (tid >= off) incl += v;
            }
            const unsigned long long bal = __ballot(incl >= k);
            const int g64 = __ffsll(bal) - 1;
            const unsigned cum64 = (unsigned)__shfl((int)(incl - ssum), g64, 64);

            const unsigned h2 = (tid < 32) ? hist[g64 * 32 + tid] : 0u;
            unsigned incl2 = h2;
#pragma unroll
            for (int off = 1; off < 64; off <<= 1) {
                const unsigned v = (unsigned)__shfl_up((int)incl2, off, 64);
                if (tid >= off) incl2 += v;
            }
            const unsigned long long bal2 =
                __ballot(tid < 32 && (cum64 + incl2 >= k));
            const int sb = __ffsll(bal2) - 1;
            const unsigned cum = cum64 + (unsigned)__shfl((int)(incl2 - h2), sb, 64);
            if (tid == 0) { s_g = (unsigned)(g64 * 32 + sb); s_cum = cum; }
        }
        __syncthreads();                                     // B5
        const unsigned g = s_g;

        // ---- Phase D: gather boundary candidates from registers ----------
#pragma unroll
        for (int it2 = 0; it2 < ITERS; ++it2) {
#pragma unroll
            for (int jj = 0; jj < 4; ++jj) {
                const unsigned bits = rbits[it2 * 4 + jj];
                const unsigned idx =
                    (unsigned)(((unsigned long long)(bits - minb) << 11) >> sh);
                if (idx == g) {
                    const unsigned w = atomicAdd(&s_ncand, 1u);
                    if (w < CAP) {
                        cand_bits[w] = bits;
                        cand_idx[w]  =
                            (unsigned short)(it2 * (TPB * 4) + tid * 4 + jj);
                    }
                }
            }
        }
        __syncthreads();                                     // B6

        // ---- Phase E: rank candidates; rank j-1 pair is the threshold ----
        const unsigned c = min(s_ncand, (unsigned)CAP);
        const unsigned j = k - s_cum;        // 1 <= j <= count(bucket g)
        for (unsigned t = tid; t < c; t += TPB) {
            const unsigned bt = cand_bits[t];
            const unsigned it = cand_idx[t];
            unsigned rank = 0;
            for (unsigned u = 0; u < c; ++u) {
                const unsigned bu = cand_bits[u];
                rank += (bu < bt) || (bu == bt && (unsigned)cand_idx[u] < it);
            }
            if (rank == j - 1) { s_Tb = bt; s_Ti = it; }  // unique pair
        }
        __syncthreads();                                     // B7
    }

    // ---- Phase F: write both masks from registers + (Tb,Ti) threshold ----
    const unsigned Tb = s_Tb, Ti = s_Ti;
#pragma unroll
    for (int it2 = 0; it2 < ITERS; ++it2) {
        const int i0 = it2 * (TPB * 4) + tid * 4;
        float4 o0, o1;
        float* o0p = &o0.x; float* o1p = &o1.x;
#pragma unroll
        for (int jj = 0; jj < 4; ++jj) {
            const unsigned bits = rbits[it2 * 4 + jj];
            const unsigned gi   = (unsigned)(i0 + jj);
            const bool sel = (bits < Tb) || (bits == Tb && gi <= Ti);
            const float mv = rm16[it2 * 4 + jj];
            o0p[jj] = sel ? 0.0f  : mv;
            o1p[jj] = sel ? 32.0f : (1.0f - mv);
        }
        *(float4*)(out0 + (size_t)b * N_ + i0) = o0;
        *(float4*)(out1 + (size_t)b * N_ + i0) = o1;
    }
}

extern "C" void kernel_launch(void* const* d_in, const int* in_sizes, int n_in,
                              void* d_out, int out_size, void* d_ws, size_t ws_size,
                              hipStream_t stream) {
    const float* pos   = (const float*)d_in[0];   // [B,N,3]
    const float* rmask = (const float*)d_in[1];   // [B,N]
    const float* apos  = (const float*)d_in[2];   // [B,A,3]
    const float* amask = (const float*)d_in[3];   // [B,A]
    // d_in[4] = max_p (unused by the reference outputs)
    const int*   topk  = (const int*)d_in[5];

    float* out0 = (float*)d_out;
    float* out1 = out0 + (size_t)B_ * N_;

    fused_kernel<<<B_, TPB, 0, stream>>>(pos, rmask, apos, amask, topk, out0, out1);
}